// Round 1
// 423.135 us; speedup vs baseline: 1.1594x; 1.1594x over previous
//
#include <hip/hip_runtime.h>
#include <hip/hip_bf16.h>

// Sizes
#define B_ 256
#define D_ 3072
#define H_ 256
#define OPT_ 32
#define OD_ 98304       // OPT_*D_
#define NL_ 4

typedef __attribute__((ext_vector_type(8))) short short8;
typedef __attribute__((ext_vector_type(4))) float f32x4;

__device__ __forceinline__ unsigned short f2bf(float f) {
    unsigned int u = __float_as_uint(f);
    unsigned int r = (u + 0x7FFFu + ((u >> 16) & 1u)) >> 16;
    return (unsigned short)r;
}

// ---------------------------------------------------------------------------
// init: cur = 0, rx = -x, zpart = 0  (grid 4096 x 256 = 1048576 threads)
__global__ __launch_bounds__(256) void init_kernel(const float* __restrict__ x,
                                                   float* __restrict__ cur,
                                                   float* __restrict__ rx,
                                                   float* __restrict__ zpart) {
    int gid = blockIdx.x * 256 + threadIdx.x;
    if (gid < B_ * D_) {
        cur[gid] = 0.f;
        rx[gid] = -x[gid];
    }
    zpart[gid] = 0.f;   // 16*B_*H_ = 1048576 exactly
}

// ---------------------------------------------------------------------------
// gemm1: zpart[ks][b][h] = sum_{d in 192-slice ks} cur[b][d] * Wb[d][h]
// grid 512 blocks (16 kslices x 32 bgroups of 8 b), 256 threads (= h)
// cur reads are wave-uniform -> scalar loads (SMEM pipe), no LDS at all.
__global__ __launch_bounds__(256) void gemm1_kernel(const float* __restrict__ cur,
                                                    const float* __restrict__ Wb,
                                                    float* __restrict__ zpart) {
    int t = threadIdx.x;
    int ks = blockIdx.x >> 5;     // 0..15
    int bg = blockIdx.x & 31;     // 0..31
    const float* wp = Wb + (size_t)ks * 192 * H_ + t;
    const float* cp = cur + (size_t)(bg * 8) * D_ + ks * 192;
    float acc[8] = {0.f, 0.f, 0.f, 0.f, 0.f, 0.f, 0.f, 0.f};
#pragma unroll 4
    for (int dd = 0; dd < 192; ++dd) {
        float w = wp[(size_t)dd * H_];
#pragma unroll
        for (int g = 0; g < 8; ++g) acc[g] += cp[(size_t)g * D_ + dd] * w;
    }
#pragma unroll
    for (int g = 0; g < 8; ++g)
        zpart[ks * (B_ * H_) + (bg * 8 + g) * H_ + t] = acc[g];
}

// ---------------------------------------------------------------------------
// E: base = relu(sum_ks zpart + bb). Writes:
//   (a) bf16 staging image: byte = (k>>5)*20480 + m*80 + (k&31)*2  (for g2)
//   (b) f32 basef[m][k]                                            (for d, scalar reads)
__global__ __launch_bounds__(256) void e_kernel(const float* __restrict__ zpart,
                                                const float* __restrict__ bb,
                                                unsigned char* __restrict__ base_ready,
                                                float* __restrict__ basef) {
    int m = blockIdx.x, k = threadIdx.x;
    float z = bb[k];
#pragma unroll
    for (int ks = 0; ks < 16; ++ks) z += zpart[ks * (B_ * H_) + m * H_ + k];
    z = z > 0.f ? z : 0.f;
    *(unsigned short*)(base_ready + (k >> 5) * 20480 + m * 80 + (k & 31) * 2) = f2bf(z);
    basef[m * H_ + k] = z;
}

// ---------------------------------------------------------------------------
// G2: fused GEMM (256x98304, K=256, bf16 MFMA) + squared-loss partials.
// grid 768 blocks (n-tiles of 128), 512 threads (8 waves: 4 m-waves x 2 n-waves)
// T14 pipeline: single barrier per K-step; loads for step s+1 issued right
// after barrier_{s-1}, in flight under MFMA of step s, written to the other
// LDS buffer before barrier_s. No load ever crosses a barrier (no vmcnt(0)
// drain of in-flight prefetch).
__global__ __launch_bounds__(512, 4) void g2_kernel(const unsigned char* __restrict__ base_ready,
                                                    const float* __restrict__ Wo,    // [256][98304] layer slice
                                                    const float* __restrict__ biasL, // [32*3072]
                                                    const float* __restrict__ boL,   // [98304]
                                                    const float* __restrict__ rx,    // [256*3072]
                                                    float* __restrict__ partial) {
    __shared__ __align__(16) unsigned char ldsA[2][20480];  // [m][32k bf16 + pad], double-buffered
    __shared__ __align__(16) unsigned char ldsW[2][10240];  // [n][32k bf16 + pad], double-buffered

    int t = threadIdx.x;
    int lane = t & 63, wv = t >> 6;
    int bx = blockIdx.x;
    int ncol0 = bx * 128;
    int o = bx / 24;                 // 24 blocks per option
    int dbase = (bx % 24) * 128;

    int wm = wv >> 1, wn = wv & 1;
    int lrow = lane & 15, lk = lane >> 4;
    int nW = t & 127, kq = t >> 7;   // W staging role: kq in 0..3

    f32x4 acc[4][4];
#pragma unroll
    for (int mi = 0; mi < 4; ++mi)
#pragma unroll
        for (int ni = 0; ni < 4; ++ni) acc[mi][ni] = 0.f;

    // prefetch registers
    uint4 pa0, pa1, pa2;
    float wf[8];

#define LOADA(S) { const unsigned char* gA = base_ready + (S) * 20480;           \
    pa0 = *(const uint4*)(gA + t * 16);                                          \
    pa1 = *(const uint4*)(gA + 8192 + t * 16);                                   \
    if (t < 256) pa2 = *(const uint4*)(gA + 16384 + t * 16); }

#define LOADW(S) {                                                               \
    const float* gp0 = Wo + (size_t)((S) * 32 + kq * 4) * OD_ + ncol0 + nW;      \
    wf[0] = gp0[0]; wf[1] = gp0[OD_]; wf[2] = gp0[2 * OD_]; wf[3] = gp0[3 * OD_];\
    const float* gp1 = gp0 + (size_t)16 * OD_;                                   \
    wf[4] = gp1[0]; wf[5] = gp1[OD_]; wf[6] = gp1[2 * OD_]; wf[7] = gp1[3 * OD_]; }

#define WRITEA(BUF) {                                                            \
    *(uint4*)(ldsA[BUF] + t * 16) = pa0;                                         \
    *(uint4*)(ldsA[BUF] + 8192 + t * 16) = pa1;                                  \
    if (t < 256) *(uint4*)(ldsA[BUF] + 16384 + t * 16) = pa2; }

#define WRITEW(BUF) {                                                            \
    uint2 pk0, pk1;                                                              \
    pk0.x = (unsigned)f2bf(wf[0]) | ((unsigned)f2bf(wf[1]) << 16);               \
    pk0.y = (unsigned)f2bf(wf[2]) | ((unsigned)f2bf(wf[3]) << 16);               \
    *(uint2*)(ldsW[BUF] + nW * 80 + kq * 8) = pk0;                               \
    pk1.x = (unsigned)f2bf(wf[4]) | ((unsigned)f2bf(wf[5]) << 16);               \
    pk1.y = (unsigned)f2bf(wf[6]) | ((unsigned)f2bf(wf[7]) << 16);               \
    *(uint2*)(ldsW[BUF] + nW * 80 + 32 + kq * 8) = pk1; }

    // prologue: stage step 0, then issue step-1 loads after the barrier
    LOADA(0); LOADW(0);
    WRITEA(0); WRITEW(0);
    __syncthreads();
    LOADA(1); LOADW(1);

    for (int s = 0; s < 8; ++s) {
        int cur = s & 1;
        short8 bfr[4];
#pragma unroll
        for (int ni = 0; ni < 4; ++ni) {
            int nn = wn * 64 + ni * 16 + lrow;
            bfr[ni] = *(const short8*)(ldsW[cur] + nn * 80 + lk * 16);
        }
#pragma unroll
        for (int mi = 0; mi < 4; ++mi) {
            int row = wm * 64 + mi * 16 + lrow;
            short8 af = *(const short8*)(ldsA[cur] + row * 80 + lk * 16);
#pragma unroll
            for (int ni = 0; ni < 4; ++ni)
                acc[mi][ni] = __builtin_amdgcn_mfma_f32_16x16x32_bf16(af, bfr[ni], acc[mi][ni], 0, 0, 0);
        }
        if (s < 7) { WRITEA(cur ^ 1); WRITEW(cur ^ 1); }   // regs hold step s+1
        __syncthreads();
        if (s < 6) { LOADA(s + 2); LOADW(s + 2); }         // fly under step s+1 MFMA
    }

#undef LOADA
#undef LOADW
#undef WRITEA
#undef WRITEW

    // epilogue: loss partials
    float q[4];
#pragma unroll
    for (int ni = 0; ni < 4; ++ni) {
        int dcol = dbase + wn * 64 + ni * 16 + lrow;
        q[ni] = biasL[o * D_ + dcol] + boL[o * D_ + dcol];
    }
    float ssum[4][4];
#pragma unroll
    for (int mi = 0; mi < 4; ++mi)
#pragma unroll
        for (int r = 0; r < 4; ++r) ssum[mi][r] = 0.f;

#pragma unroll
    for (int mi = 0; mi < 4; ++mi) {
#pragma unroll
        for (int ni = 0; ni < 4; ++ni) {
            int dcol = dbase + wn * 64 + ni * 16 + lrow;
#pragma unroll
            for (int r = 0; r < 4; ++r) {
                int rowm = wm * 64 + mi * 16 + lk * 4 + r;
                float tv = acc[mi][ni][r] + rx[rowm * D_ + dcol] + q[ni];
                ssum[mi][r] += tv * tv;
            }
        }
    }
#pragma unroll
    for (int mi = 0; mi < 4; ++mi)
#pragma unroll
        for (int r = 0; r < 4; ++r) {
            float v = ssum[mi][r];
            v += __shfl_xor(v, 1);
            v += __shfl_xor(v, 2);
            v += __shfl_xor(v, 4);
            v += __shfl_xor(v, 8);
            if (lrow == 0) {
                int rowm = wm * 64 + mi * 16 + lk * 4 + r;
                partial[(rowm * OPT_ + o) * 48 + (bx % 24) * 2 + wn] = v;
            }
        }
}

// ---------------------------------------------------------------------------
// C: per-b argmin over 32 options. 256 threads: 8 threads per option, all
// 32x48 partials loaded in parallel; tie-break = lowest index (jnp.argmin).
__global__ __launch_bounds__(256) void c_kernel(const float* __restrict__ partial,
                                                int* __restrict__ idxbuf,
                                                float* __restrict__ enc, int layer) {
    __shared__ float ls[32];
    int b = blockIdx.x, t = threadIdx.x;
    int oo = t >> 3, j8 = t & 7;
    const float* pp = partial + (b * OPT_ + oo) * 48;
    float v = 0.f;
#pragma unroll
    for (int j = 0; j < 6; ++j) v += pp[j8 + 8 * j];
    v += __shfl_xor(v, 1);
    v += __shfl_xor(v, 2);
    v += __shfl_xor(v, 4);
    if (j8 == 0) ls[oo] = v;
    __syncthreads();
    if (t < 32) {
        float mv = ls[t];
        int mi = t;
#pragma unroll
        for (int m = 16; m >= 1; m >>= 1) {
            float ov = __shfl_xor(mv, m);
            int oi = __shfl_xor(mi, m);
            if (ov < mv || (ov == mv && oi < mi)) { mv = ov; mi = oi; }
        }
        if (t == 0) {
            idxbuf[b] = mi;
            enc[b * NL_ + layer] = (float)mi;
        }
    }
}

// ---------------------------------------------------------------------------
// D: recompute selected option, update cur and rx = cur - x.
// grid (32 bq x 12 dt), 256 threads. base reads are wave-uniform -> scalar
// loads from basef (no LDS); w-loads batched 4-wide for MLP pipelining.
__global__ __launch_bounds__(256) void d_kernel(const int* __restrict__ idxbuf,
                                                const float* __restrict__ basef,
                                                const float* __restrict__ Wo,
                                                const float* __restrict__ boL,
                                                const float* __restrict__ biasL,
                                                const float* __restrict__ x,
                                                float* __restrict__ cur,
                                                float* __restrict__ rx) {
    int t = threadIdx.x;
    int bq = blockIdx.x, dt = blockIdx.y;
    int d = dt * 256 + t;
    const float* bp = basef + bq * 8 * H_;
    int oL[8];
#pragma unroll
    for (int g = 0; g < 8; ++g) oL[g] = idxbuf[bq * 8 + g];
    bool uni = true;
#pragma unroll
    for (int g = 1; g < 8; ++g) uni = uni && (oL[g] == oL[0]);

    float acc[8] = {0.f, 0.f, 0.f, 0.f, 0.f, 0.f, 0.f, 0.f};
    if (uni) {
        const float* wp = Wo + (size_t)oL[0] * D_ + d;
#pragma unroll 2
        for (int k0 = 0; k0 < 256; k0 += 4) {
            float w0 = wp[(size_t)(k0 + 0) * OD_];
            float w1 = wp[(size_t)(k0 + 1) * OD_];
            float w2 = wp[(size_t)(k0 + 2) * OD_];
            float w3 = wp[(size_t)(k0 + 3) * OD_];
#pragma unroll
            for (int g = 0; g < 8; ++g) {
                acc[g] += bp[g * H_ + k0] * w0 + bp[g * H_ + k0 + 1] * w1
                        + bp[g * H_ + k0 + 2] * w2 + bp[g * H_ + k0 + 3] * w3;
            }
        }
    } else {
        for (int k = 0; k < 256; ++k) {
#pragma unroll
            for (int g = 0; g < 8; ++g)
                acc[g] += bp[g * H_ + k] * Wo[(size_t)k * OD_ + (size_t)oL[g] * D_ + d];
        }
    }
#pragma unroll
    for (int g = 0; g < 8; ++g) {
        int b = bq * 8 + g;
        size_t nn = (size_t)oL[g] * D_ + d;
        float outv = cur[b * D_ + d] + acc[g] + boL[nn] + biasL[nn];
        cur[b * D_ + d] = outv;
        rx[b * D_ + d] = outv - x[b * D_ + d];
    }
}

// ---------------------------------------------------------------------------
extern "C" void kernel_launch(void* const* d_in, const int* in_sizes, int n_in,
                              void* d_out, int out_size, void* d_ws, size_t ws_size,
                              hipStream_t stream) {
    const float* x    = (const float*)d_in[0];  // [256][3072]
    const float* Wb   = (const float*)d_in[1];  // [3072][256]
    const float* bb   = (const float*)d_in[2];  // [256]
    const float* Wo   = (const float*)d_in[3];  // [4][256][98304]
    const float* bo   = (const float*)d_in[4];  // [4][98304]
    const float* bias = (const float*)d_in[5];  // [4][32][3072]

    float* out = (float*)d_out;
    float* enc = out;            // [256][4] (indices as float)
    float* cur = out + 1024;     // [256][3072] reconstruction

    float* ws = (float*)d_ws;
    float* zpart   = ws;                          // 16*256*256 = 1048576
    float* partial = ws + 1048576;                // 256*32*48  = 393216
    float* rx      = ws + 1441792;                // 256*3072   = 786432
    float* basef   = ws + 2228224;                // 256*256    = 65536
    unsigned char* base_ready = (unsigned char*)(ws + 2293760);  // 163840 B
    int* idxbuf    = (int*)(ws + 2334720);        // 256 ints

    init_kernel<<<4096, 256, 0, stream>>>(x, cur, rx, zpart);

    for (int i = 0; i < NL_; ++i) {
        const float* WoL   = Wo + (size_t)i * H_ * OD_;
        const float* boLp  = bo + (size_t)i * OD_;
        const float* biasL = bias + (size_t)i * OD_;
        if (i > 0) gemm1_kernel<<<512, 256, 0, stream>>>(cur, Wb, zpart);
        e_kernel<<<256, 256, 0, stream>>>(zpart, bb, base_ready, basef);
        g2_kernel<<<768, 512, 0, stream>>>(base_ready, WoL, biasL, boLp, rx, partial);
        c_kernel<<<256, 256, 0, stream>>>(partial, idxbuf, enc, i);
        d_kernel<<<dim3(32, 12), 256, 0, stream>>>(idxbuf, basef, WoL, boLp, biasL, x, cur, rx);
    }
}